// Round 1
// baseline (519.332 us; speedup 1.0000x reference)
//
#include <hip/hip_runtime.h>
#include <hip/hip_bf16.h>

#define S_ 256
#define DIM_ 1024
#define BT_ 512
#define SOFTCAP_ 50.0f
#define EPS_ 1e-6f

typedef __attribute__((ext_vector_type(8))) short bf16x8;
typedef __attribute__((ext_vector_type(4))) float f32x4;

__device__ __forceinline__ unsigned short f2bf(float f) {
    unsigned u = __float_as_uint(f);
    u += 0x7FFFu + ((u >> 16) & 1u);
    return (unsigned short)(u >> 16);
}

// ---------------- Wkv -> bf16 fragment-layout swizzle ----------------
// layout: [kb(32)][nb(32)][lane(64)][j(8)]  value = W'[kb*32+(l>>4)*8+j][nb*16+(l&15)]
// n<256 -> Wk col n ; n>=256 -> Wv col n-256
__global__ void wkv_swizzle(const float* __restrict__ Wk, const float* __restrict__ Wv,
                            unsigned short* __restrict__ wkv) {
    int tid = blockIdx.x * 256 + threadIdx.x;   // 0..65535
    int l = tid & 63;
    int nb = (tid >> 6) & 31;
    int kb = tid >> 11;
    int n = nb * 16 + (l & 15);
    int kbase = kb * 32 + ((l >> 4) << 3);
    const float* src = (n < 256) ? (Wk + n) : (Wv + (n - 256));
    unsigned short r[8];
#pragma unroll
    for (int j = 0; j < 8; ++j) r[j] = f2bf(src[(size_t)(kbase + j) * 256]);
    uint4 o;
    o.x = (unsigned)r[0] | ((unsigned)r[1] << 16);
    o.y = (unsigned)r[2] | ((unsigned)r[3] << 16);
    o.z = (unsigned)r[4] | ((unsigned)r[5] << 16);
    o.w = (unsigned)r[6] | ((unsigned)r[7] << 16);
    *(uint4*)(wkv + (size_t)tid * 8) = o;
}

// ---------------- Q projection + RMSNorm ----------------
// grid (4 colgroups, 64 rowgroups), 256 threads. 8 rows/block, 1 col/thread.
__global__ __launch_bounds__(256) void qproj_kernel(
    const float* __restrict__ agent, const float* __restrict__ Wq,
    const float* __restrict__ q_gamma, float* __restrict__ ws_q)
{
    __shared__ float srows[8][1024];
    int cg = blockIdx.x, rg = blockIdx.y;
    int t = threadIdx.x;
#pragma unroll
    for (int j = 0; j < 8; ++j) {
        int f = j * 256 + t;          // float4 index 0..2047
        int row = f >> 8, c4 = f & 255;
        *(float4*)&srows[row][c4 * 4] =
            *(const float4*)(agent + (size_t)(rg * 8 + row) * 1024 + c4 * 4);
    }
    __syncthreads();
    int c = cg * 256 + t;
    float acc[8] = {0, 0, 0, 0, 0, 0, 0, 0};
    for (int k = 0; k < 1024; k += 4) {
        float w0 = Wq[(size_t)(k + 0) * 1024 + c];
        float w1 = Wq[(size_t)(k + 1) * 1024 + c];
        float w2 = Wq[(size_t)(k + 2) * 1024 + c];
        float w3 = Wq[(size_t)(k + 3) * 1024 + c];
#pragma unroll
        for (int r = 0; r < 8; ++r) {
            float4 a = *(const float4*)&srows[r][k];
            acc[r] += a.x * w0 + a.y * w1 + a.z * w2 + a.w * w3;
        }
    }
    float g = q_gamma[c & 63];
#pragma unroll
    for (int r = 0; r < 8; ++r) {
        float ss = acc[r] * acc[r];
        ss += __shfl_xor(ss, 1);  ss += __shfl_xor(ss, 2);
        ss += __shfl_xor(ss, 4);  ss += __shfl_xor(ss, 8);
        ss += __shfl_xor(ss, 16); ss += __shfl_xor(ss, 32);
        float rs = rsqrtf(ss * (1.0f / 64.0f) + EPS_);
        ws_q[(size_t)(rg * 8 + r) * 1024 + c] = acc[r] * rs * g;
    }
}

// ---------------- Fused KV projection + attention ----------------
// 1 block per (b,t). 4 waves; wave w = kv head w (owns K cols w*64.. and V cols 256+w*64..).
__global__ __launch_bounds__(256, 2) void kv_attn_kernel(
    const float* __restrict__ z, const unsigned short* __restrict__ wkv,
    const float* __restrict__ ws_q, const float* __restrict__ k_gamma,
    float* __restrict__ ws_att)
{
    __shared__ __align__(16) unsigned short ldsA[64 * 256];   // 32KB, XOR-swizzled bf16
    const int bt = blockIdx.x;
    const int tid = threadIdx.x;
    const int w = tid >> 6;
    const int l = tid & 63;
    const int l15 = l & 15;
    const int lg = l >> 4;
    const float* zb = z + (size_t)bt * (S_ * DIM_);

    float qn[4][4], kgm[4];
#pragma unroll
    for (int g = 0; g < 4; ++g)
#pragma unroll
        for (int ni = 0; ni < 4; ++ni)
            qn[g][ni] = ws_q[(size_t)bt * 1024 + (4 * w + g) * 64 + ni * 16 + l15];
#pragma unroll
    for (int ni = 0; ni < 4; ++ni) kgm[ni] = k_gamma[ni * 16 + l15];

    float out_acc[4][4] = {};
    float denom[4] = {};

    for (int c = 0; c < 4; ++c) {                 // 4 chunks of 64 s-rows
        f32x4 acc[4][8];
#pragma unroll
        for (int mi = 0; mi < 4; ++mi)
#pragma unroll
            for (int ni = 0; ni < 8; ++ni) acc[mi][ni] = (f32x4){0.f, 0.f, 0.f, 0.f};

        for (int sl = 0; sl < 4; ++sl) {          // k-slices of 256
            __syncthreads();
#pragma unroll
            for (int j = 0; j < 16; ++j) {        // stage 64x256 fp32 -> bf16 LDS
                int f = j * 256 + tid;            // float4 idx 0..4095
                int row = f >> 6, c4 = f & 63;
                float4 v4 = *(const float4*)(zb + (size_t)(c * 64 + row) * DIM_ + sl * 256 + c4 * 4);
                uint2 pk;
                pk.x = (unsigned)f2bf(v4.x) | ((unsigned)f2bf(v4.y) << 16);
                pk.y = (unsigned)f2bf(v4.z) | ((unsigned)f2bf(v4.w) << 16);
                int byteoff = ((row * 512) + c4 * 8) ^ ((row & 7) << 4);
                *(uint2*)((char*)ldsA + byteoff) = pk;
            }
            __syncthreads();
#pragma unroll
            for (int ksl = 0; ksl < 8; ++ksl) {
                const int ks = sl * 8 + ksl;      // global k-step 0..31
                bf16x8 a[4], b[8];
#pragma unroll
                for (int mi = 0; mi < 4; ++mi) {
                    int row = mi * 16 + l15;
                    int byteoff = ((row * 512) + ksl * 64 + lg * 16) ^ ((row & 7) << 4);
                    a[mi] = *(const bf16x8*)((const char*)ldsA + byteoff);
                }
#pragma unroll
                for (int ni = 0; ni < 8; ++ni) {
                    int nb = (ni < 4) ? (w * 4 + ni) : (16 + w * 4 + ni - 4);
                    b[ni] = *(const bf16x8*)(wkv + ((size_t)(ks * 32 + nb) * 64 + l) * 8);
                }
#pragma unroll
                for (int mi = 0; mi < 4; ++mi)
#pragma unroll
                    for (int ni = 0; ni < 8; ++ni)
                        acc[mi][ni] = __builtin_amdgcn_mfma_f32_16x16x32_bf16(
                            a[mi], b[ni], acc[mi][ni], 0, 0, 0);
            }
        }
        // ---- attention for this chunk (all in-register; rows live in this wave) ----
#pragma unroll
        for (int mi = 0; mi < 4; ++mi) {
#pragma unroll
            for (int r = 0; r < 4; ++r) {
                float k0 = acc[mi][0][r], k1 = acc[mi][1][r], k2 = acc[mi][2][r], k3 = acc[mi][3][r];
                float ss = k0 * k0 + k1 * k1 + k2 * k2 + k3 * k3;
                ss += __shfl_xor(ss, 1); ss += __shfl_xor(ss, 2);
                ss += __shfl_xor(ss, 4); ss += __shfl_xor(ss, 8);
                float rs = rsqrtf(ss * (1.0f / 64.0f) + EPS_);
                k0 *= rs * kgm[0]; k1 *= rs * kgm[1]; k2 *= rs * kgm[2]; k3 *= rs * kgm[3];
#pragma unroll
                for (int g = 0; g < 4; ++g) {
                    float sp = qn[g][0] * k0 + qn[g][1] * k1 + qn[g][2] * k2 + qn[g][3] * k3;
                    sp += __shfl_xor(sp, 1); sp += __shfl_xor(sp, 2);
                    sp += __shfl_xor(sp, 4); sp += __shfl_xor(sp, 8);
                    float sc = sp * 0.125f;                    // * hd^-0.5
                    float e2 = __expf(sc * (2.0f / SOFTCAP_)); // e^(2x), x=sc/50
                    float th = 1.0f - 2.0f / (e2 + 1.0f);      // tanh(x)
                    float p = __expf(SOFTCAP_ * th);           // no max-sub: |capped|<=50 safe in fp32
                    denom[g] += p;
                    out_acc[g][0] += p * acc[mi][4][r];
                    out_acc[g][1] += p * acc[mi][5][r];
                    out_acc[g][2] += p * acc[mi][6][r];
                    out_acc[g][3] += p * acc[mi][7][r];
                }
            }
        }
    }
    // cross-lane-group reduce (rows are spread over lg=0..3), normalize, write
#pragma unroll
    for (int g = 0; g < 4; ++g) {
        float d = denom[g];
        d += __shfl_xor(d, 16); d += __shfl_xor(d, 32);
        float inv = 1.0f / d;
#pragma unroll
        for (int nv = 0; nv < 4; ++nv) {
            float o = out_acc[g][nv];
            o += __shfl_xor(o, 16); o += __shfl_xor(o, 32);
            if (lg == 0)
                ws_att[(size_t)bt * 1024 + (4 * w + g) * 64 + nv * 16 + l15] = o * inv;
        }
    }
}

// ---------------- Output projection ----------------
__global__ __launch_bounds__(256) void oproj_kernel(
    const float* __restrict__ att, const float* __restrict__ Wo,
    float* __restrict__ out)
{
    __shared__ float srows[8][1024];
    int cg = blockIdx.x, rg = blockIdx.y;
    int t = threadIdx.x;
#pragma unroll
    for (int j = 0; j < 8; ++j) {
        int f = j * 256 + t;
        int row = f >> 8, c4 = f & 255;
        *(float4*)&srows[row][c4 * 4] =
            *(const float4*)(att + (size_t)(rg * 8 + row) * 1024 + c4 * 4);
    }
    __syncthreads();
    int c = cg * 256 + t;
    float acc[8] = {0, 0, 0, 0, 0, 0, 0, 0};
    for (int k = 0; k < 1024; k += 4) {
        float w0 = Wo[(size_t)(k + 0) * 1024 + c];
        float w1 = Wo[(size_t)(k + 1) * 1024 + c];
        float w2 = Wo[(size_t)(k + 2) * 1024 + c];
        float w3 = Wo[(size_t)(k + 3) * 1024 + c];
#pragma unroll
        for (int r = 0; r < 8; ++r) {
            float4 a = *(const float4*)&srows[r][k];
            acc[r] += a.x * w0 + a.y * w1 + a.z * w2 + a.w * w3;
        }
    }
#pragma unroll
    for (int r = 0; r < 8; ++r)
        out[(size_t)(rg * 8 + r) * 1024 + c] = acc[r];
}

extern "C" void kernel_launch(void* const* d_in, const int* in_sizes, int n_in,
                              void* d_out, int out_size, void* d_ws, size_t ws_size,
                              hipStream_t stream) {
    const float* agent = (const float*)d_in[0];
    const float* z     = (const float*)d_in[1];
    const float* Wq    = (const float*)d_in[2];
    const float* Wk    = (const float*)d_in[3];
    const float* Wv    = (const float*)d_in[4];
    const float* Wo    = (const float*)d_in[5];
    const float* qg    = (const float*)d_in[6];
    const float* kg    = (const float*)d_in[7];
    float* out = (float*)d_out;

    char* ws = (char*)d_ws;
    float* ws_q   = (float*)ws;                          // 2 MB
    float* ws_att = (float*)(ws + (2u << 20));           // 2 MB
    unsigned short* ws_wkv = (unsigned short*)(ws + (4u << 20)); // 1 MB

    hipLaunchKernelGGL(wkv_swizzle, dim3(256), dim3(256), 0, stream, Wk, Wv, ws_wkv);
    hipLaunchKernelGGL(qproj_kernel, dim3(4, 64), dim3(256), 0, stream, agent, Wq, qg, ws_q);
    hipLaunchKernelGGL(kv_attn_kernel, dim3(512), dim3(256), 0, stream, z, ws_wkv, ws_q, kg, ws_att);
    hipLaunchKernelGGL(oproj_kernel, dim3(4, 64), dim3(256), 0, stream, ws_att, Wo, out);
}